// Round 3
// baseline (1900.171 us; speedup 1.0000x reference)
//
#include <hip/hip_runtime.h>

#define NN 100000
#define MPAD 100096
#define NT_M 782

typedef unsigned short u16;
typedef __attribute__((ext_vector_type(8))) short bf16x8;
typedef __attribute__((ext_vector_type(4))) float f32x4;

__device__ __forceinline__ u16 f2bf(float f){
  union { float f; unsigned u; } v; v.f=f;
  unsigned u = v.u + 0x7fffu + ((v.u>>16)&1u);
  return (u16)(u>>16);
}
__device__ __forceinline__ float bf2f(u16 b){
  union { unsigned u; float f; } v; v.u = ((unsigned)b)<<16; return v.f;
}
__device__ __forceinline__ void gload16(const void* g, void* l){
  __builtin_amdgcn_global_load_lds((const __attribute__((address_space(1))) void*)g,
                                   (__attribute__((address_space(3))) void*)l, 16, 0, 0);
}
__device__ __forceinline__ void lds_fence(){
  asm volatile("s_waitcnt lgkmcnt(0)" ::: "memory");
  __builtin_amdgcn_wave_barrier();
}

// ---------------- split-precision GEMM: C[m,n] = sum_k A[m,k]*B[n,k]
// A as hi/lo bf16 pair (up to 3 sub-buffers of 256 cols along K), B as hi/lo pair.
// acc += Ah*Bh + Al*Bh + Ah*Bl  (error ~2^-18 relative)
// EPI 0: split-store bf16 hi/lo to chi/clo. EPI 1: out = (acc + tvec[col])*rnorm[row] (f32).
template<int EPI>
__global__ __launch_bounds__(256) void k_gemm(
  const u16* __restrict__ ah0, const u16* __restrict__ al0,
  const u16* __restrict__ ah1, const u16* __restrict__ al1,
  const u16* __restrict__ ah2, const u16* __restrict__ al2,
  const u16* __restrict__ bh, const u16* __restrict__ bl,
  u16* __restrict__ chi, u16* __restrict__ clo,
  float* __restrict__ outf, const float* __restrict__ tvec,
  const float* __restrict__ rnorm, int Bstride, int KT)
{
  __shared__ u16 lds[2][4][4096];   // [buf][Ah,Al,Bh,Bl][128 rows x 32 cols]
  const int tid=threadIdx.x, lane=tid&63, wid=tid>>6;
  const int wr=wid>>1, wc=wid&1;
  const long m0=(long)blockIdx.x*128;
  const int n0=blockIdx.y*128;
  f32x4 acc[4][4]={};

  auto stageT=[&](u16* L, const u16* G, int rs){
    #pragma unroll
    for(int i=0;i<2;i++){
      int idx=i*256+tid;
      int row=idx>>2, c8=idx&3;
      int gc=(c8^(row&3))*8;              // chunk-XOR swizzle on the GLOBAL side
      gload16(G+(long)row*rs+gc, L+idx*8);
    }
  };
  auto stage=[&](int buf,int kt){
    const u16 *Ah,*Al; int kc;
    if(kt<8){Ah=ah0;Al=al0;kc=kt*32;}
    else if(kt<16){Ah=ah1;Al=al1;kc=(kt-8)*32;}
    else {Ah=ah2;Al=al2;kc=(kt-16)*32;}
    stageT(lds[buf][0], Ah+m0*256+kc, 256);
    stageT(lds[buf][1], Al+m0*256+kc, 256);
    stageT(lds[buf][2], bh+(long)n0*Bstride+kt*32, Bstride);
    stageT(lds[buf][3], bl+(long)n0*Bstride+kt*32, Bstride);
  };
  stage(0,0);
  __syncthreads();
  int buf=0;
  for(int kt=0;kt<KT;kt++){
    if(kt+1<KT) stage(buf^1,kt+1);
    const u16* LAh=lds[buf][0]; const u16* LAl=lds[buf][1];
    const u16* LBh=lds[buf][2]; const u16* LBl=lds[buf][3];
    bf16x8 avh[4],avl[4],bvh[4],bvl[4];
    #pragma unroll
    for(int mf=0;mf<4;mf++){
      int r=wr*64+mf*16+(lane&15);
      int ch=((lane>>4)^(r&3))*8;         // same XOR on the read side
      avh[mf]=*(const bf16x8*)&LAh[r*32+ch];
      avl[mf]=*(const bf16x8*)&LAl[r*32+ch];
    }
    #pragma unroll
    for(int nf=0;nf<4;nf++){
      int r=wc*64+nf*16+(lane&15);
      int ch=((lane>>4)^(r&3))*8;
      bvh[nf]=*(const bf16x8*)&LBh[r*32+ch];
      bvl[nf]=*(const bf16x8*)&LBl[r*32+ch];
    }
    #pragma unroll
    for(int mf=0;mf<4;mf++){
      #pragma unroll
      for(int nf=0;nf<4;nf++){
        acc[mf][nf]=__builtin_amdgcn_mfma_f32_16x16x32_bf16(avh[mf],bvh[nf],acc[mf][nf],0,0,0);
        acc[mf][nf]=__builtin_amdgcn_mfma_f32_16x16x32_bf16(avl[mf],bvh[nf],acc[mf][nf],0,0,0);
        acc[mf][nf]=__builtin_amdgcn_mfma_f32_16x16x32_bf16(avh[mf],bvl[nf],acc[mf][nf],0,0,0);
      }
    }
    __syncthreads();
    buf^=1;
  }
  #pragma unroll
  for(int mf=0;mf<4;mf++){
    #pragma unroll
    for(int j=0;j<4;j++){
      long row=m0+wr*64+mf*16+((lane>>4)*4)+j;
      if(row<NN){
        #pragma unroll
        for(int nf=0;nf<4;nf++){
          int col=n0+wc*64+nf*16+(lane&15);
          float v=acc[mf][nf][j];
          if(EPI==1){
            outf[row*256+col]=(v+tvec[col])*rnorm[row];
          } else {
            u16 h=f2bf(v);
            chi[row*256+col]=h;
            clo[row*256+col]=f2bf(v-bf2f(h));
          }
        }
      }
    }
  }
}

// ---------------- x patch moments
__global__ __launch_bounds__(256) void k_xmom(const float* __restrict__ x, float* __restrict__ stats){
  int t=blockIdx.x*blockDim.x+threadIdx.x, stride=gridDim.x*blockDim.x;
  int lane=threadIdx.x&63;
  float m[5]={0,0,0,0,0};
  float c[15]={0,0,0,0,0,0,0,0,0,0,0,0,0,0,0};
  for(int n=t;n<NN;n+=stride){
    float xr[60];
    #pragma unroll
    for(int i=0;i<15;i++){
      float4 v=*(const float4*)&x[(long)n*60+i*4];
      xr[i*4]=v.x; xr[i*4+1]=v.y; xr[i*4+2]=v.z; xr[i*4+3]=v.w;
    }
    #pragma unroll
    for(int p=0;p<12;p++){
      float vv[5]={xr[5*p],xr[5*p+1],xr[5*p+2],xr[5*p+3],xr[5*p+4]};
      #pragma unroll
      for(int k=0;k<5;k++) m[k]+=vv[k];
      int idx=0;
      #pragma unroll
      for(int k=0;k<5;k++){
        #pragma unroll
        for(int k2=k;k2<5;k2++){ c[idx]+=vv[k]*vv[k2]; idx++; }
      }
    }
  }
  float vals[20];
  #pragma unroll
  for(int i=0;i<5;i++) vals[i]=m[i];
  #pragma unroll
  for(int i=0;i<15;i++) vals[5+i]=c[i];
  #pragma unroll
  for(int i=0;i<20;i++){
    float v=vals[i];
    #pragma unroll
    for(int off=32;off;off>>=1) v+=__shfl_xor(v,off);
    if(lane==0) atomicAdd(&stats[i],v);
  }
}

__global__ void k_fin1(const float* __restrict__ stats, const float* __restrict__ w1,
                       const float* __restrict__ b1, const float* __restrict__ g,
                       const float* __restrict__ bt, float* __restrict__ a1c1){
  int c=threadIdx.x;
  if(c>=32) return;
  const float inv=1.0f/(NN*12.0f);
  float mu[5];
  for(int k=0;k<5;k++) mu[k]=stats[k]*inv;
  float C[5][5];
  int idx=5;
  for(int k=0;k<5;k++) for(int k2=k;k2<5;k2++){ float v=stats[idx++]*inv; C[k][k2]=v; C[k2][k]=v; }
  float wv[5];
  for(int k=0;k<5;k++) wv[k]=w1[c*5+k];
  float bb=b1[c];
  float mean=bb, e2=bb*bb;
  for(int k=0;k<5;k++){ mean+=wv[k]*mu[k]; e2+=2.f*bb*wv[k]*mu[k]; }
  for(int k=0;k<5;k++) for(int k2=0;k2<5;k2++) e2+=wv[k]*wv[k2]*C[k][k2];
  float var=e2-mean*mean;
  float a=g[c]*rsqrtf(var+1e-5f);
  a1c1[c]=a; a1c1[32+c]=bt[c]-mean*a;
}

// conv1->bn1/relu->conv2. PASS 0: accumulate BN2 stats. PASS 1: apply bn2+relu, split-store h.
template<int PASS>
__global__ __launch_bounds__(256) void k_conv(const float* __restrict__ x,
  const float* __restrict__ w1, const float* __restrict__ b1,
  const float* __restrict__ a1c1, const float* __restrict__ w2,
  const float* __restrict__ b2, const float* __restrict__ a2c2,
  u16* __restrict__ hH, u16* __restrict__ hL, float* __restrict__ stats2)
{
  __shared__ float w2s[64*97];
  __shared__ float w1s[160], a1s[32], c1s[32], b1s[32], b2s[64];
  __shared__ float xs[4][64];
  __shared__ float z1s[4][384];
  __shared__ float bsum[128];
  int tid=threadIdx.x, lane=tid&63, w=tid>>6;
  for(int i=tid;i<6144;i+=256) w2s[(i/96)*97+(i%96)]=w2[i];
  if(tid<160) w1s[tid]=w1[tid];
  if(tid<32){ a1s[tid]=a1c1[tid]; c1s[tid]=a1c1[32+tid]; b1s[tid]=b1[tid]; }
  if(tid<64) b2s[tid]=b2[tid];
  if(PASS==0 && tid<128) bsum[tid]=0.f;
  __syncthreads();
  float ssum=0.f, ssq=0.f;
  float a2=0.f, c2v=0.f;
  if(PASS==1){ a2=a2c2[lane]; c2v=a2c2[64+lane]; }
  int gw=blockIdx.x*4+w, nw=gridDim.x*4;
  for(int n=gw;n<NN;n+=nw){
    if(lane<60) xs[w][lane]=x[(long)n*60+lane];
    lds_fence();
    {
      int c=lane>>1, pb=(lane&1)*6;
      float av=a1s[c], cv=c1s[c], bb=b1s[c];
      #pragma unroll
      for(int i=0;i<6;i++){
        int p=pb+i;
        float y=bb;
        #pragma unroll
        for(int k=0;k<5;k++) y+=xs[w][5*p+k]*w1s[c*5+k];
        z1s[w][c*12+p]=fmaxf(y*av+cv,0.f);
      }
    }
    lds_fence();
    {
      int c2=lane;
      float acc0=b2s[c2],acc1=b2s[c2],acc2=b2s[c2],acc3=b2s[c2];
      #pragma unroll
      for(int ci=0;ci<32;ci++){
        float4 za=*(const float4*)&z1s[w][ci*12];
        float4 zb=*(const float4*)&z1s[w][ci*12+4];
        float4 zc=*(const float4*)&z1s[w][ci*12+8];
        float w0=w2s[c2*97+ci*3], wv1=w2s[c2*97+ci*3+1], wv2=w2s[c2*97+ci*3+2];
        acc0 += za.x*w0+za.y*wv1+za.z*wv2;
        acc1 += za.w*w0+zb.x*wv1+zb.y*wv2;
        acc2 += zb.z*w0+zb.w*wv1+zc.x*wv2;
        acc3 += zc.y*w0+zc.z*wv1+zc.w*wv2;
      }
      if(PASS==0){
        ssum+=acc0+acc1+acc2+acc3;
        ssq+=acc0*acc0+acc1*acc1+acc2*acc2+acc3*acc3;
      } else {
        float o0=fmaxf(acc0*a2+c2v,0.f), o1=fmaxf(acc1*a2+c2v,0.f);
        float o2=fmaxf(acc2*a2+c2v,0.f), o3=fmaxf(acc3*a2+c2v,0.f);
        ushort4 hi, lo;
        hi.x=f2bf(o0); lo.x=f2bf(o0-bf2f(hi.x));
        hi.y=f2bf(o1); lo.y=f2bf(o1-bf2f(hi.y));
        hi.z=f2bf(o2); lo.z=f2bf(o2-bf2f(hi.z));
        hi.w=f2bf(o3); lo.w=f2bf(o3-bf2f(hi.w));
        *(ushort4*)&hH[(long)n*256+c2*4]=hi;
        *(ushort4*)&hL[(long)n*256+c2*4]=lo;
      }
    }
    lds_fence();
  }
  if(PASS==0){
    atomicAdd(&bsum[lane],ssum);
    atomicAdd(&bsum[64+lane],ssq);
    __syncthreads();
    if(tid<128) atomicAdd(&stats2[tid],bsum[tid]);
  }
}

__global__ void k_fin2(const float* __restrict__ stats2, const float* __restrict__ g,
                       const float* __restrict__ bt, float* __restrict__ a2c2){
  int c=threadIdx.x;
  if(c>=64) return;
  const float inv=1.0f/(NN*4.0f);
  float mean=stats2[c]*inv;
  float var=stats2[64+c]*inv-mean*mean;
  float a=g[c]*rsqrtf(var+1e-5f);
  a2c2[c]=a; a2c2[64+c]=bt[c]-mean*a;
}

// f32 -> bf16 hi/lo split
__global__ void k_cvt2(const float* __restrict__ in, u16* __restrict__ oh, u16* __restrict__ ol, int n){
  int i=blockIdx.x*blockDim.x+threadIdx.x;
  if(i<n){
    float v=in[i];
    u16 h=f2bf(v);
    oh[i]=h; ol[i]=f2bf(v-bf2f(h));
  }
}

// fold dbn scale into l2-normalized cos_W rows; also t[r] = sum_k c_k * Wn_k / ||Wn||
__global__ __launch_bounds__(256) void k_wfold(const float* __restrict__ cw, const float* __restrict__ ab,
  u16* __restrict__ wh, u16* __restrict__ wl, float* __restrict__ tvec)
{
  int lane=threadIdx.x&63;
  int r=blockIdx.x*4+(threadIdx.x>>6);
  if(r>=256) return;
  float v[12]; float ss=0.f, tn=0.f;
  #pragma unroll
  for(int i=0;i<12;i++){
    int col=i*64+lane;
    v[i]=cw[r*768+col];
    ss+=v[i]*v[i];
    tn+=v[i]*ab[768+col];
  }
  #pragma unroll
  for(int off=32;off;off>>=1){ ss+=__shfl_xor(ss,off); tn+=__shfl_xor(tn,off); }
  float sc=1.0f/fmaxf(sqrtf(ss),1e-12f);
  #pragma unroll
  for(int i=0;i<12;i++){
    int col=i*64+lane;
    float wv=v[i]*sc*ab[col];
    u16 h=f2bf(wv);
    wh[r*768+col]=h; wl[r*768+col]=f2bf(wv-bf2f(h));
  }
  if(lane==0) tvec[r]=tn*sc;
}

// el/er per node from split feat
__global__ __launch_bounds__(256) void k_elr(const u16* __restrict__ fH, const u16* __restrict__ fL,
  const float* __restrict__ al, const float* __restrict__ ar,
  float* __restrict__ el, float* __restrict__ er)
{
  int lane=threadIdx.x&63;
  int gw=blockIdx.x*4+(threadIdx.x>>6), nw=gridDim.x*4;
  int head=lane>>5, cb=lane*4;
  float4 alv=*(const float4*)&al[cb];
  float4 arv=*(const float4*)&ar[cb];
  for(int n=gw;n<NN;n+=nw){
    ushort4 fh=*(const ushort4*)&fH[(long)n*256+cb];
    ushort4 fl=*(const ushort4*)&fL[(long)n*256+cb];
    float x0=bf2f(fh.x)+bf2f(fl.x), x1=bf2f(fh.y)+bf2f(fl.y);
    float x2=bf2f(fh.z)+bf2f(fl.z), x3=bf2f(fh.w)+bf2f(fl.w);
    float pel=x0*alv.x+x1*alv.y+x2*alv.z+x3*alv.w;
    float per=x0*arv.x+x1*arv.y+x2*arv.z+x3*arv.w;
    #pragma unroll
    for(int off=16;off;off>>=1){ pel+=__shfl_xor(pel,off); per+=__shfl_xor(per,off); }
    if((lane&31)==0){ el[2*n+head]=pel; er[2*n+head]=per; }
  }
}

template<int ACT> __device__ __forceinline__ float actf(float g);
template<> __device__ __forceinline__ float actf<1>(float g){
  float t=tanhf(g);
  float ls=fminf(g,0.f)-log1pf(__expf(-fabsf(g)));
  return fmaxf(g,0.f)+t+ls;
}
template<> __device__ __forceinline__ float actf<2>(float g){ return tanhf(g); }
template<> __device__ __forceinline__ float actf<3>(float g){ return fmaxf(g,0.f); }

// per-node 16-edge softmax + gather (split feat) -> split h_next + dbn stats
template<int ACT>
__global__ __launch_bounds__(256) void k_aggr(const u16* __restrict__ fH, const u16* __restrict__ fL,
  const float* __restrict__ el, const float* __restrict__ er,
  const int* __restrict__ src, const float* __restrict__ bias,
  u16* __restrict__ hH, u16* __restrict__ hL, float* __restrict__ dbn_raw, int col_base)
{
  __shared__ float bsum[256], bsq[256];
  int tid=threadIdx.x, lane=tid&63;
  bsum[tid]=0.f; bsq[tid]=0.f;
  __syncthreads();
  int gw=blockIdx.x*4+(tid>>6), nw=gridDim.x*4;
  int head=lane>>5, cb=lane*4;
  float4 b4=*(const float4*)&bias[cb];
  float s[4]={0,0,0,0}, q[4]={0,0,0,0};
  for(int n=gw;n<NN;n+=nw){
    int sidx[16];
    #pragma unroll
    for(int j=0;j<16;j+=4){
      int4 v=*(const int4*)&src[n*16+j];
      sidx[j]=v.x; sidx[j+1]=v.y; sidx[j+2]=v.z; sidx[j+3]=v.w;
    }
    float er0=er[2*n], er1=er[2*n+1];
    float e0[16], e1[16];
    float mx0=-1e30f, mx1=-1e30f;
    #pragma unroll
    for(int j=0;j<16;j++){
      float a=el[2*sidx[j]]+er0;
      float bb=el[2*sidx[j]+1]+er1;
      a = a>0.f? a : 0.2f*a;
      bb = bb>0.f? bb : 0.2f*bb;
      e0[j]=a; e1[j]=bb;
      mx0=fmaxf(mx0,a); mx1=fmaxf(mx1,bb);
    }
    float d0=0.f,d1=0.f;
    #pragma unroll
    for(int j=0;j<16;j++){
      e0[j]=__expf(e0[j]-mx0); d0+=e0[j];
      e1[j]=__expf(e1[j]-mx1); d1+=e1[j];
    }
    float r0=1.f/fmaxf(d0,1e-12f), r1=1.f/fmaxf(d1,1e-12f);
    float a0=b4.x,a1=b4.y,a2=b4.z,a3=b4.w;
    #pragma unroll
    for(int j=0;j<16;j++){
      float aw=head? e1[j]*r1 : e0[j]*r0;
      long base=(long)sidx[j]*256+cb;
      ushort4 fh=*(const ushort4*)&fH[base];
      ushort4 fl=*(const ushort4*)&fL[base];
      a0+=aw*(bf2f(fh.x)+bf2f(fl.x));
      a1+=aw*(bf2f(fh.y)+bf2f(fl.y));
      a2+=aw*(bf2f(fh.z)+bf2f(fl.z));
      a3+=aw*(bf2f(fh.w)+bf2f(fl.w));
    }
    float h0=actf<ACT>(a0), h1=actf<ACT>(a1), h2=actf<ACT>(a2), h3=actf<ACT>(a3);
    ushort4 hi, lo;
    hi.x=f2bf(h0); lo.x=f2bf(h0-bf2f(hi.x));
    hi.y=f2bf(h1); lo.y=f2bf(h1-bf2f(hi.y));
    hi.z=f2bf(h2); lo.z=f2bf(h2-bf2f(hi.z));
    hi.w=f2bf(h3); lo.w=f2bf(h3-bf2f(hi.w));
    *(ushort4*)&hH[(long)n*256+cb]=hi;
    *(ushort4*)&hL[(long)n*256+cb]=lo;
    s[0]+=h0; s[1]+=h1; s[2]+=h2; s[3]+=h3;
    q[0]+=h0*h0; q[1]+=h1*h1; q[2]+=h2*h2; q[3]+=h3*h3;
  }
  #pragma unroll
  for(int i=0;i<4;i++){ atomicAdd(&bsum[cb+i], s[i]); atomicAdd(&bsq[cb+i], q[i]); }
  __syncthreads();
  atomicAdd(&dbn_raw[col_base+tid], bsum[tid]);
  atomicAdd(&dbn_raw[768+col_base+tid], bsq[tid]);
}

__global__ void k_dbnfin(const float* __restrict__ raw, const float* __restrict__ g,
                         const float* __restrict__ b, float* __restrict__ ab){
  int c=blockIdx.x*blockDim.x+threadIdx.x;
  if(c<768){
    float mean=raw[c]*(1.0f/NN);
    float var=raw[768+c]*(1.0f/NN)-mean*mean;
    float a=g[c]*rsqrtf(var+1e-5f);
    ab[c]=a; ab[768+c]=b[c]-mean*a;
  }
}

// rnorm[n] = 4.6 / || dbn(h1|h2|h3) ||  from split h
__global__ __launch_bounds__(256) void k_rnorm(
  const u16* __restrict__ h1h, const u16* __restrict__ h1l,
  const u16* __restrict__ h2h, const u16* __restrict__ h2l,
  const u16* __restrict__ h3h, const u16* __restrict__ h3l,
  const float* __restrict__ ab, float* __restrict__ rn)
{
  int lane=threadIdx.x&63;
  int gw=blockIdx.x*4+(threadIdx.x>>6), nw=gridDim.x*4;
  int cb=lane*4;
  float av[12], cv[12];
  #pragma unroll
  for(int s=0;s<3;s++){
    #pragma unroll
    for(int i=0;i<4;i++){ av[s*4+i]=ab[s*256+cb+i]; cv[s*4+i]=ab[768+s*256+cb+i]; }
  }
  for(int n=gw;n<NN;n+=nw){
    float ss=0.f;
    const u16* hh[3]={h1h,h2h,h3h};
    const u16* hl[3]={h1l,h2l,h3l};
    #pragma unroll
    for(int s=0;s<3;s++){
      ushort4 a4=*(const ushort4*)&hh[s][(long)n*256+cb];
      ushort4 c4=*(const ushort4*)&hl[s][(long)n*256+cb];
      float o0=(bf2f(a4.x)+bf2f(c4.x))*av[s*4+0]+cv[s*4+0];
      float o1=(bf2f(a4.y)+bf2f(c4.y))*av[s*4+1]+cv[s*4+1];
      float o2=(bf2f(a4.z)+bf2f(c4.z))*av[s*4+2]+cv[s*4+2];
      float o3=(bf2f(a4.w)+bf2f(c4.w))*av[s*4+3]+cv[s*4+3];
      ss+=o0*o0+o1*o1+o2*o2+o3*o3;
    }
    #pragma unroll
    for(int off=32;off;off>>=1) ss+=__shfl_xor(ss,off);
    if(lane==0) rn[n]=4.6f/fmaxf(sqrtf(ss),1e-12f);
  }
}

extern "C" void kernel_launch(void* const* d_in, const int* in_sizes, int n_in,
                              void* d_out, int out_size, void* d_ws, size_t ws_size,
                              hipStream_t stream)
{
  (void)in_sizes; (void)n_in; (void)out_size; (void)ws_size;
  const float* x   =(const float*)d_in[0];
  const int*   src =(const int*)d_in[1];
  const float* w1  =(const float*)d_in[3];
  const float* b1  =(const float*)d_in[4];
  const float* bn1g=(const float*)d_in[5];
  const float* bn1b=(const float*)d_in[6];
  const float* w2  =(const float*)d_in[7];
  const float* b2  =(const float*)d_in[8];
  const float* bn2g=(const float*)d_in[9];
  const float* bn2b=(const float*)d_in[10];
  const float* fc1 =(const float*)d_in[11];
  const float* a1l =(const float*)d_in[12];
  const float* a1r =(const float*)d_in[13];
  const float* bias1=(const float*)d_in[14];
  const float* fc2 =(const float*)d_in[15];
  const float* a2l =(const float*)d_in[16];
  const float* a2r =(const float*)d_in[17];
  const float* bias2=(const float*)d_in[18];
  const float* dbng=(const float*)d_in[19];
  const float* dbnb=(const float*)d_in[20];
  const float* cw  =(const float*)d_in[21];

  char* ws=(char*)d_ws;
  size_t off=0;
  auto take=[&](size_t bytes)->char*{ char* p=ws+off; off=(off+bytes+255)&~(size_t)255; return p; };
  float* stats =(float*)take(2048*4);
  float* params=(float*)take(2048*4);
  float* el    =(float*)take((size_t)MPAD*2*4);
  float* er    =(float*)take((size_t)MPAD*2*4);
  float* rnorm =(float*)take((size_t)MPAD*4);
  float* tvec  =(float*)take(256*4);
  u16* fc1h=(u16*)take((size_t)65536*2);
  u16* fc1l=(u16*)take((size_t)65536*2);
  u16* fc2h=(u16*)take((size_t)65536*2);
  u16* fc2l=(u16*)take((size_t)65536*2);
  u16* wfh =(u16*)take((size_t)196608*2);
  u16* wfl =(u16*)take((size_t)196608*2);
  const size_t FB=(size_t)MPAD*256*2;
  u16* h0H  =(u16*)take(FB); u16* h0L  =(u16*)take(FB);  // conv h; later h3
  u16* h1H  =(u16*)take(FB); u16* h1L  =(u16*)take(FB);
  u16* h2H  =(u16*)take(FB); u16* h2L  =(u16*)take(FB);
  // feat pair lives in d_out (scratch until the final GEMM): 2*NN*256*2B == NN*256*4B exactly
  u16* featH=(u16*)d_out;
  u16* featL=featH+(size_t)NN*256;

  float* xmom   =stats;        // 20
  float* stats2 =stats+32;     // 128
  float* dbn_raw=stats+512;    // 1536
  float* a1c1   =params;       // 64
  float* a2c2   =params+64;    // 128
  float* dbn_ab =params+256;   // 1536

  hipMemsetAsync(stats,0,2048*4,stream);
  k_cvt2<<<dim3(256),dim3(256),0,stream>>>(fc1,fc1h,fc1l,65536);
  k_cvt2<<<dim3(256),dim3(256),0,stream>>>(fc2,fc2h,fc2l,65536);
  k_xmom<<<dim3(128),dim3(256),0,stream>>>(x,xmom);
  k_fin1<<<dim3(1),dim3(64),0,stream>>>(xmom,w1,b1,bn1g,bn1b,a1c1);
  k_conv<0><<<dim3(1024),dim3(256),0,stream>>>(x,w1,b1,a1c1,w2,b2,a2c2,h0H,h0L,stats2);
  k_fin2<<<dim3(1),dim3(64),0,stream>>>(stats2,bn2g,bn2b,a2c2);
  k_conv<1><<<dim3(1024),dim3(256),0,stream>>>(x,w1,b1,a1c1,w2,b2,a2c2,h0H,h0L,stats2);

  dim3 gg(NT_M,2);
  // GAT layer 1
  k_gemm<0><<<gg,dim3(256),0,stream>>>(h0H,h0L,h0H,h0L,h0H,h0L,fc1h,fc1l,featH,featL,
                                       (float*)nullptr,tvec,rnorm,256,8);
  k_elr<<<dim3(1024),dim3(256),0,stream>>>(featH,featL,a1l,a1r,el,er);
  k_aggr<1><<<dim3(1024),dim3(256),0,stream>>>(featH,featL,el,er,src,bias1,h1H,h1L,dbn_raw,0);
  // GAT layer 2
  k_gemm<0><<<gg,dim3(256),0,stream>>>(h1H,h1L,h1H,h1L,h1H,h1L,fc2h,fc2l,featH,featL,
                                       (float*)nullptr,tvec,rnorm,256,8);
  k_elr<<<dim3(1024),dim3(256),0,stream>>>(featH,featL,a2l,a2r,el,er);
  k_aggr<2><<<dim3(1024),dim3(256),0,stream>>>(featH,featL,el,er,src,bias2,h2H,h2L,dbn_raw,256);
  // GAT layer 3
  k_gemm<0><<<gg,dim3(256),0,stream>>>(h2H,h2L,h2H,h2L,h2H,h2L,fc2h,fc2l,featH,featL,
                                       (float*)nullptr,tvec,rnorm,256,8);
  k_elr<<<dim3(1024),dim3(256),0,stream>>>(featH,featL,a2l,a2r,el,er);
  k_aggr<3><<<dim3(1024),dim3(256),0,stream>>>(featH,featL,el,er,src,bias2,h0H,h0L,dbn_raw,512);
  // dbn + folded cosine head
  k_dbnfin<<<dim3(3),dim3(256),0,stream>>>(dbn_raw,dbng,dbnb,dbn_ab);
  k_wfold<<<dim3(64),dim3(256),0,stream>>>(cw,dbn_ab,wfh,wfl,tvec);
  k_rnorm<<<dim3(1024),dim3(256),0,stream>>>(h1H,h1L,h2H,h2L,h0H,h0L,dbn_ab,rnorm);
  k_gemm<1><<<gg,dim3(256),0,stream>>>(h1H,h1L,h2H,h2L,h0H,h0L,wfh,wfl,(u16*)nullptr,(u16*)nullptr,
                                       (float*)d_out,tvec,rnorm,768,24);
}

// Round 4
// 1572.129 us; speedup vs baseline: 1.2087x; 1.2087x over previous
//
#include <hip/hip_runtime.h>

#define NN 100000
#define MPAD 100096
#define NT_M 782

typedef unsigned short u16;
typedef __attribute__((ext_vector_type(8))) short bf16x8;
typedef __attribute__((ext_vector_type(4))) float f32x4;

__device__ __forceinline__ u16 f2bf(float f){
  union { float f; unsigned u; } v; v.f=f;
  unsigned u = v.u + 0x7fffu + ((v.u>>16)&1u);
  return (u16)(u>>16);
}
__device__ __forceinline__ float bf2f(u16 b){
  union { unsigned u; float f; } v; v.u = ((unsigned)b)<<16; return v.f;
}
__device__ __forceinline__ void gload16(const void* g, void* l){
  __builtin_amdgcn_global_load_lds((const __attribute__((address_space(1))) void*)g,
                                   (__attribute__((address_space(3))) void*)l, 16, 0, 0);
}
__device__ __forceinline__ void lds_fence(){
  asm volatile("s_waitcnt lgkmcnt(0)" ::: "memory");
  __builtin_amdgcn_wave_barrier();
}

// ---------------- split-precision GEMM: C[m,n] = sum_k A[m,k]*B[n,k]
// A as hi/lo bf16 pair (up to 3 sub-buffers of 256 cols along K), B as hi/lo pair.
// acc += Ah*Bh + Al*Bh + Ah*Bl  (error ~2^-18 relative)
// EPI 0: store bf16 hi to chi. EPI 1: out = (acc + tvec[col])*rnorm[row] (f32).
template<int EPI>
__global__ __launch_bounds__(256) void k_gemm(
  const u16* __restrict__ ah0, const u16* __restrict__ al0,
  const u16* __restrict__ ah1, const u16* __restrict__ al1,
  const u16* __restrict__ ah2, const u16* __restrict__ al2,
  const u16* __restrict__ bh, const u16* __restrict__ bl,
  u16* __restrict__ chi,
  float* __restrict__ outf, const float* __restrict__ tvec,
  const float* __restrict__ rnorm, int Bstride, int KT)
{
  __shared__ u16 lds[2][4][4096];   // [buf][Ah,Al,Bh,Bl][128 rows x 32 cols]
  const int tid=threadIdx.x, lane=tid&63, wid=tid>>6;
  const int wr=wid>>1, wc=wid&1;
  const long m0=(long)blockIdx.x*128;
  const int n0=blockIdx.y*128;
  f32x4 acc[4][4]={};

  auto stageT=[&](u16* L, const u16* G, int rs){
    #pragma unroll
    for(int i=0;i<2;i++){
      int idx=i*256+tid;
      int row=idx>>2, c8=idx&3;
      int gc=(c8^(row&3))*8;              // chunk-XOR swizzle on the GLOBAL side
      gload16(G+(long)row*rs+gc, L+idx*8);
    }
  };
  auto stage=[&](int buf,int kt){
    const u16 *Ah,*Al; int kc;
    if(kt<8){Ah=ah0;Al=al0;kc=kt*32;}
    else if(kt<16){Ah=ah1;Al=al1;kc=(kt-8)*32;}
    else {Ah=ah2;Al=al2;kc=(kt-16)*32;}
    stageT(lds[buf][0], Ah+m0*256+kc, 256);
    stageT(lds[buf][1], Al+m0*256+kc, 256);
    stageT(lds[buf][2], bh+(long)n0*Bstride+kt*32, Bstride);
    stageT(lds[buf][3], bl+(long)n0*Bstride+kt*32, Bstride);
  };
  stage(0,0);
  __syncthreads();
  int buf=0;
  for(int kt=0;kt<KT;kt++){
    if(kt+1<KT) stage(buf^1,kt+1);
    const u16* LAh=lds[buf][0]; const u16* LAl=lds[buf][1];
    const u16* LBh=lds[buf][2]; const u16* LBl=lds[buf][3];
    bf16x8 avh[4],avl[4],bvh[4],bvl[4];
    #pragma unroll
    for(int mf=0;mf<4;mf++){
      int r=wr*64+mf*16+(lane&15);
      int ch=((lane>>4)^(r&3))*8;         // same XOR on the read side
      avh[mf]=*(const bf16x8*)&LAh[r*32+ch];
      avl[mf]=*(const bf16x8*)&LAl[r*32+ch];
    }
    #pragma unroll
    for(int nf=0;nf<4;nf++){
      int r=wc*64+nf*16+(lane&15);
      int ch=((lane>>4)^(r&3))*8;
      bvh[nf]=*(const bf16x8*)&LBh[r*32+ch];
      bvl[nf]=*(const bf16x8*)&LBl[r*32+ch];
    }
    #pragma unroll
    for(int mf=0;mf<4;mf++){
      #pragma unroll
      for(int nf=0;nf<4;nf++){
        acc[mf][nf]=__builtin_amdgcn_mfma_f32_16x16x32_bf16(avh[mf],bvh[nf],acc[mf][nf],0,0,0);
        acc[mf][nf]=__builtin_amdgcn_mfma_f32_16x16x32_bf16(avl[mf],bvh[nf],acc[mf][nf],0,0,0);
        acc[mf][nf]=__builtin_amdgcn_mfma_f32_16x16x32_bf16(avh[mf],bvl[nf],acc[mf][nf],0,0,0);
      }
    }
    __syncthreads();
    buf^=1;
  }
  #pragma unroll
  for(int mf=0;mf<4;mf++){
    #pragma unroll
    for(int j=0;j<4;j++){
      long row=m0+wr*64+mf*16+((lane>>4)*4)+j;
      if(row<NN){
        #pragma unroll
        for(int nf=0;nf<4;nf++){
          int col=n0+wc*64+nf*16+(lane&15);
          float v=acc[mf][nf][j];
          if(EPI==1) outf[row*256+col]=(v+tvec[col])*rnorm[row];
          else       chi[row*256+col]=f2bf(v);
        }
      }
    }
  }
}

// ---------------- x patch moments
__global__ __launch_bounds__(256) void k_xmom(const float* __restrict__ x, float* __restrict__ stats){
  int t=blockIdx.x*blockDim.x+threadIdx.x, stride=gridDim.x*blockDim.x;
  int lane=threadIdx.x&63;
  float m[5]={0,0,0,0,0};
  float c[15]={0,0,0,0,0,0,0,0,0,0,0,0,0,0,0};
  for(int n=t;n<NN;n+=stride){
    float xr[60];
    #pragma unroll
    for(int i=0;i<15;i++){
      float4 v=*(const float4*)&x[(long)n*60+i*4];
      xr[i*4]=v.x; xr[i*4+1]=v.y; xr[i*4+2]=v.z; xr[i*4+3]=v.w;
    }
    #pragma unroll
    for(int p=0;p<12;p++){
      float vv[5]={xr[5*p],xr[5*p+1],xr[5*p+2],xr[5*p+3],xr[5*p+4]};
      #pragma unroll
      for(int k=0;k<5;k++) m[k]+=vv[k];
      int idx=0;
      #pragma unroll
      for(int k=0;k<5;k++){
        #pragma unroll
        for(int k2=k;k2<5;k2++){ c[idx]+=vv[k]*vv[k2]; idx++; }
      }
    }
  }
  float vals[20];
  #pragma unroll
  for(int i=0;i<5;i++) vals[i]=m[i];
  #pragma unroll
  for(int i=0;i<15;i++) vals[5+i]=c[i];
  #pragma unroll
  for(int i=0;i<20;i++){
    float v=vals[i];
    #pragma unroll
    for(int off=32;off;off>>=1) v+=__shfl_xor(v,off);
    if(lane==0) atomicAdd(&stats[i],v);
  }
}

__global__ void k_fin1(const float* __restrict__ stats, const float* __restrict__ w1,
                       const float* __restrict__ b1, const float* __restrict__ g,
                       const float* __restrict__ bt, float* __restrict__ a1c1){
  int c=threadIdx.x;
  if(c>=32) return;
  const float inv=1.0f/(NN*12.0f);
  float mu[5];
  for(int k=0;k<5;k++) mu[k]=stats[k]*inv;
  float C[5][5];
  int idx=5;
  for(int k=0;k<5;k++) for(int k2=k;k2<5;k2++){ float v=stats[idx++]*inv; C[k][k2]=v; C[k2][k]=v; }
  float wv[5];
  for(int k=0;k<5;k++) wv[k]=w1[c*5+k];
  float bb=b1[c];
  float mean=bb, e2=bb*bb;
  for(int k=0;k<5;k++){ mean+=wv[k]*mu[k]; e2+=2.f*bb*wv[k]*mu[k]; }
  for(int k=0;k<5;k++) for(int k2=0;k2<5;k2++) e2+=wv[k]*wv[k2]*C[k][k2];
  float var=e2-mean*mean;
  float a=g[c]*rsqrtf(var+1e-5f);
  a1c1[c]=a; a1c1[32+c]=bt[c]-mean*a;
}

// transform vectors: v[vec][k], vec = {L1h0,L1h1,R1h0,R1h1,L2h0,L2h1,R2h0,R2h1}
// vL[h][k] = sum_c fc[h*128+c, k] * a[h,c]   (so el[n,h] = sum_k h[n,k] vL[h][k])
__global__ void k_prep(const float* __restrict__ fc1, const float* __restrict__ fc2,
                       const float* __restrict__ a1l, const float* __restrict__ a1r,
                       const float* __restrict__ a2l, const float* __restrict__ a2r,
                       float* __restrict__ vprep){
  int k=threadIdx.x;
  float acc[8]={0,0,0,0,0,0,0,0};
  for(int r=0;r<256;r++){
    int h=r>>7, c=r&127;
    float f1=fc1[r*256+k], f2=fc2[r*256+k];
    acc[0+h]+=f1*a1l[h*128+c];
    acc[2+h]+=f1*a1r[h*128+c];
    acc[4+h]+=f2*a2l[h*128+c];
    acc[6+h]+=f2*a2r[h*128+c];
  }
  #pragma unroll
  for(int v=0;v<8;v++) vprep[v*256+k]=acc[v];
}

// conv1->bn1/relu->conv2. PASS 0: BN2 stats. PASS 1: apply bn2+relu, split-store h, + layer-1 el/er.
template<int PASS>
__global__ __launch_bounds__(256) void k_conv(const float* __restrict__ x,
  const float* __restrict__ w1, const float* __restrict__ b1,
  const float* __restrict__ a1c1, const float* __restrict__ w2,
  const float* __restrict__ b2, const float* __restrict__ a2c2,
  u16* __restrict__ hH, u16* __restrict__ hL, float* __restrict__ stats2,
  const float* __restrict__ vprep, float* __restrict__ elv, float* __restrict__ erv)
{
  __shared__ float w2s[64*97];
  __shared__ float w1s[160], a1s[32], c1s[32], b1s[32], b2s[64];
  __shared__ float xs[4][64];
  __shared__ float z1s[4][384];
  __shared__ float bsum[128];
  int tid=threadIdx.x, lane=tid&63, w=tid>>6;
  for(int i=tid;i<6144;i+=256) w2s[(i/96)*97+(i%96)]=w2[i];
  if(tid<160) w1s[tid]=w1[tid];
  if(tid<32){ a1s[tid]=a1c1[tid]; c1s[tid]=a1c1[32+tid]; b1s[tid]=b1[tid]; }
  if(tid<64) b2s[tid]=b2[tid];
  if(PASS==0 && tid<128) bsum[tid]=0.f;
  __syncthreads();
  float ssum=0.f, ssq=0.f;
  float a2=0.f, c2v=0.f;
  float4 vl0={0,0,0,0},vl1={0,0,0,0},vr0={0,0,0,0},vr1={0,0,0,0};
  if(PASS==1){
    a2=a2c2[lane]; c2v=a2c2[64+lane];
    int cb=lane*4;
    vl0=*(const float4*)&vprep[cb];
    vl1=*(const float4*)&vprep[256+cb];
    vr0=*(const float4*)&vprep[512+cb];
    vr1=*(const float4*)&vprep[768+cb];
  }
  int gw=blockIdx.x*4+w, nw=gridDim.x*4;
  for(int n=gw;n<NN;n+=nw){
    if(lane<60) xs[w][lane]=x[(long)n*60+lane];
    lds_fence();
    {
      int c=lane>>1, pb=(lane&1)*6;
      float av=a1s[c], cv=c1s[c], bb=b1s[c];
      #pragma unroll
      for(int i=0;i<6;i++){
        int p=pb+i;
        float y=bb;
        #pragma unroll
        for(int k=0;k<5;k++) y+=xs[w][5*p+k]*w1s[c*5+k];
        z1s[w][c*12+p]=fmaxf(y*av+cv,0.f);
      }
    }
    lds_fence();
    {
      int c2=lane;
      float acc0=b2s[c2],acc1=b2s[c2],acc2=b2s[c2],acc3=b2s[c2];
      #pragma unroll
      for(int ci=0;ci<32;ci++){
        float4 za=*(const float4*)&z1s[w][ci*12];
        float4 zb=*(const float4*)&z1s[w][ci*12+4];
        float4 zc=*(const float4*)&z1s[w][ci*12+8];
        float w0=w2s[c2*97+ci*3], wv1=w2s[c2*97+ci*3+1], wv2=w2s[c2*97+ci*3+2];
        acc0 += za.x*w0+za.y*wv1+za.z*wv2;
        acc1 += za.w*w0+zb.x*wv1+zb.y*wv2;
        acc2 += zb.z*w0+zb.w*wv1+zc.x*wv2;
        acc3 += zc.y*w0+zc.z*wv1+zc.w*wv2;
      }
      if(PASS==0){
        ssum+=acc0+acc1+acc2+acc3;
        ssq+=acc0*acc0+acc1*acc1+acc2*acc2+acc3*acc3;
      } else {
        float o0=fmaxf(acc0*a2+c2v,0.f), o1=fmaxf(acc1*a2+c2v,0.f);
        float o2=fmaxf(acc2*a2+c2v,0.f), o3=fmaxf(acc3*a2+c2v,0.f);
        ushort4 hi, lo;
        hi.x=f2bf(o0); lo.x=f2bf(o0-bf2f(hi.x));
        hi.y=f2bf(o1); lo.y=f2bf(o1-bf2f(hi.y));
        hi.z=f2bf(o2); lo.z=f2bf(o2-bf2f(hi.z));
        hi.w=f2bf(o3); lo.w=f2bf(o3-bf2f(hi.w));
        *(ushort4*)&hH[(long)n*256+c2*4]=hi;
        *(ushort4*)&hL[(long)n*256+c2*4]=lo;
        // layer-1 el/er epilogue (fp32, full-wave reduce)
        float pl0=o0*vl0.x+o1*vl0.y+o2*vl0.z+o3*vl0.w;
        float pl1=o0*vl1.x+o1*vl1.y+o2*vl1.z+o3*vl1.w;
        float pr0=o0*vr0.x+o1*vr0.y+o2*vr0.z+o3*vr0.w;
        float pr1=o0*vr1.x+o1*vr1.y+o2*vr1.z+o3*vr1.w;
        #pragma unroll
        for(int off2=32;off2;off2>>=1){
          pl0+=__shfl_xor(pl0,off2); pl1+=__shfl_xor(pl1,off2);
          pr0+=__shfl_xor(pr0,off2); pr1+=__shfl_xor(pr1,off2);
        }
        if(lane==0){ elv[2*n]=pl0; elv[2*n+1]=pl1; erv[2*n]=pr0; erv[2*n+1]=pr1; }
      }
    }
    lds_fence();
  }
  if(PASS==0){
    atomicAdd(&bsum[lane],ssum);
    atomicAdd(&bsum[64+lane],ssq);
    __syncthreads();
    if(tid<128) atomicAdd(&stats2[tid],bsum[tid]);
  }
}

__global__ void k_fin2(const float* __restrict__ stats2, const float* __restrict__ g,
                       const float* __restrict__ bt, float* __restrict__ a2c2){
  int c=threadIdx.x;
  if(c>=64) return;
  const float inv=1.0f/(NN*4.0f);
  float mean=stats2[c]*inv;
  float var=stats2[64+c]*inv-mean*mean;
  float a=g[c]*rsqrtf(var+1e-5f);
  a2c2[c]=a; a2c2[64+c]=bt[c]-mean*a;
}

// f32 -> bf16 hi/lo split
__global__ void k_cvt2(const float* __restrict__ in, u16* __restrict__ oh, u16* __restrict__ ol, int n){
  int i=blockIdx.x*blockDim.x+threadIdx.x;
  if(i<n){
    float v=in[i];
    u16 h=f2bf(v);
    oh[i]=h; ol[i]=f2bf(v-bf2f(h));
  }
}

// fold dbn scale into l2-normalized cos_W rows; t[r] = sum_k c_k * Wn_k / ||Wn||
__global__ __launch_bounds__(256) void k_wfold(const float* __restrict__ cw, const float* __restrict__ ab,
  u16* __restrict__ wh, u16* __restrict__ wl, float* __restrict__ tvec)
{
  int lane=threadIdx.x&63;
  int r=blockIdx.x*4+(threadIdx.x>>6);
  if(r>=256) return;
  float v[12]; float ss=0.f, tn=0.f;
  #pragma unroll
  for(int i=0;i<12;i++){
    int col=i*64+lane;
    v[i]=cw[r*768+col];
    ss+=v[i]*v[i];
    tn+=v[i]*ab[768+col];
  }
  #pragma unroll
  for(int off=32;off;off>>=1){ ss+=__shfl_xor(ss,off); tn+=__shfl_xor(tn,off); }
  float sc=1.0f/fmaxf(sqrtf(ss),1e-12f);
  #pragma unroll
  for(int i=0;i<12;i++){
    int col=i*64+lane;
    float wv=v[i]*sc*ab[col];
    u16 h=f2bf(wv);
    wh[r*768+col]=h; wl[r*768+col]=f2bf(wv-bf2f(h));
  }
  if(lane==0) tvec[r]=tn*sc;
}

// per-node softmax over 16 contiguous edges -> alpha[n*32 + 2j + head]
__global__ __launch_bounds__(256) void k_alpha(const float* __restrict__ el, const float* __restrict__ er,
  const int* __restrict__ srcv, float* __restrict__ alpha)
{
  int n=blockIdx.x*blockDim.x+threadIdx.x;
  if(n>=NN) return;
  int sidx[16];
  #pragma unroll
  for(int j=0;j<16;j+=4){
    int4 v=*(const int4*)&srcv[n*16+j];
    sidx[j]=v.x; sidx[j+1]=v.y; sidx[j+2]=v.z; sidx[j+3]=v.w;
  }
  float er0=er[2*n], er1=er[2*n+1];
  float e0[16], e1[16];
  float mx0=-1e30f, mx1=-1e30f;
  #pragma unroll
  for(int j=0;j<16;j++){
    float a=el[2*sidx[j]]+er0;
    float bb=el[2*sidx[j]+1]+er1;
    a = a>0.f? a : 0.2f*a;
    bb = bb>0.f? bb : 0.2f*bb;
    e0[j]=a; e1[j]=bb;
    mx0=fmaxf(mx0,a); mx1=fmaxf(mx1,bb);
  }
  float d0=0.f,d1=0.f;
  #pragma unroll
  for(int j=0;j<16;j++){
    e0[j]=__expf(e0[j]-mx0); d0+=e0[j];
    e1[j]=__expf(e1[j]-mx1); d1+=e1[j];
  }
  float r0=1.f/fmaxf(d0,1e-12f), r1=1.f/fmaxf(d1,1e-12f);
  #pragma unroll
  for(int j=0;j<16;j++){
    float2 o; o.x=e0[j]*r0; o.y=e1[j]*r1;
    ((float2*)alpha)[(long)n*16+j]=o;
  }
}

template<int ACT> __device__ __forceinline__ float actf(float g);
template<> __device__ __forceinline__ float actf<1>(float g){
  float t=tanhf(g);
  float ls=fminf(g,0.f)-log1pf(__expf(-fabsf(g)));
  return fmaxf(g,0.f)+t+ls;
}
template<> __device__ __forceinline__ float actf<2>(float g){ return tanhf(g); }
template<> __device__ __forceinline__ float actf<3>(float g){ return fmaxf(g,0.f); }

// gather-aggregate with precomputed alpha; split-store h + dbn stats; optional next-layer el/er
template<int ACT,int WELR>
__global__ __launch_bounds__(256) void k_aggr(const u16* __restrict__ fH,
  const float* __restrict__ alpha, const int* __restrict__ srcv, const float* __restrict__ bias,
  u16* __restrict__ hH, u16* __restrict__ hL, float* __restrict__ dbn_raw, int col_base,
  const float* __restrict__ vnext, float* __restrict__ elo, float* __restrict__ ero)
{
  __shared__ float bsum[256], bsq[256];
  int tid=threadIdx.x, lane=tid&63;
  bsum[tid]=0.f; bsq[tid]=0.f;
  __syncthreads();
  int gw=blockIdx.x*4+(tid>>6), nw=gridDim.x*4;
  int head=lane>>5, cb=lane*4;
  float4 b4=*(const float4*)&bias[cb];
  float4 vl0={0,0,0,0},vl1={0,0,0,0},vr0={0,0,0,0},vr1={0,0,0,0};
  if(WELR){
    vl0=*(const float4*)&vnext[cb];
    vl1=*(const float4*)&vnext[256+cb];
    vr0=*(const float4*)&vnext[512+cb];
    vr1=*(const float4*)&vnext[768+cb];
  }
  float s[4]={0,0,0,0}, q[4]={0,0,0,0};
  for(int n=gw;n<NN;n+=nw){
    int sidx[16];
    #pragma unroll
    for(int j=0;j<16;j+=4){
      int4 v=*(const int4*)&srcv[n*16+j];
      sidx[j]=v.x; sidx[j+1]=v.y; sidx[j+2]=v.z; sidx[j+3]=v.w;
    }
    float a0=b4.x,a1=b4.y,a2=b4.z,a3=b4.w;
    #pragma unroll
    for(int j=0;j<16;j++){
      float2 aw2=((const float2*)alpha)[(long)n*16+j];
      float aw = head? aw2.y : aw2.x;
      ushort4 f=*(const ushort4*)&fH[(long)sidx[j]*256+cb];
      a0+=aw*bf2f(f.x); a1+=aw*bf2f(f.y);
      a2+=aw*bf2f(f.z); a3+=aw*bf2f(f.w);
    }
    float h0=actf<ACT>(a0), h1=actf<ACT>(a1), h2=actf<ACT>(a2), h3=actf<ACT>(a3);
    ushort4 hi, lo;
    hi.x=f2bf(h0); lo.x=f2bf(h0-bf2f(hi.x));
    hi.y=f2bf(h1); lo.y=f2bf(h1-bf2f(hi.y));
    hi.z=f2bf(h2); lo.z=f2bf(h2-bf2f(hi.z));
    hi.w=f2bf(h3); lo.w=f2bf(h3-bf2f(hi.w));
    *(ushort4*)&hH[(long)n*256+cb]=hi;
    *(ushort4*)&hL[(long)n*256+cb]=lo;
    s[0]+=h0; s[1]+=h1; s[2]+=h2; s[3]+=h3;
    q[0]+=h0*h0; q[1]+=h1*h1; q[2]+=h2*h2; q[3]+=h3*h3;
    if(WELR){
      float pl0=h0*vl0.x+h1*vl0.y+h2*vl0.z+h3*vl0.w;
      float pl1=h0*vl1.x+h1*vl1.y+h2*vl1.z+h3*vl1.w;
      float pr0=h0*vr0.x+h1*vr0.y+h2*vr0.z+h3*vr0.w;
      float pr1=h0*vr1.x+h1*vr1.y+h2*vr1.z+h3*vr1.w;
      #pragma unroll
      for(int off2=32;off2;off2>>=1){
        pl0+=__shfl_xor(pl0,off2); pl1+=__shfl_xor(pl1,off2);
        pr0+=__shfl_xor(pr0,off2); pr1+=__shfl_xor(pr1,off2);
      }
      if(lane==0){ elo[2*n]=pl0; elo[2*n+1]=pl1; ero[2*n]=pr0; ero[2*n+1]=pr1; }
    }
  }
  #pragma unroll
  for(int i=0;i<4;i++){ atomicAdd(&bsum[cb+i], s[i]); atomicAdd(&bsq[cb+i], q[i]); }
  __syncthreads();
  atomicAdd(&dbn_raw[col_base+tid], bsum[tid]);
  atomicAdd(&dbn_raw[768+col_base+tid], bsq[tid]);
}

__global__ void k_dbnfin(const float* __restrict__ raw, const float* __restrict__ g,
                         const float* __restrict__ b, float* __restrict__ ab){
  int c=blockIdx.x*blockDim.x+threadIdx.x;
  if(c<768){
    float mean=raw[c]*(1.0f/NN);
    float var=raw[768+c]*(1.0f/NN)-mean*mean;
    float a=g[c]*rsqrtf(var+1e-5f);
    ab[c]=a; ab[768+c]=b[c]-mean*a;
  }
}

// rnorm[n] = 4.6 / || dbn(h1|h2|h3) ||  from split h
__global__ __launch_bounds__(256) void k_rnorm(
  const u16* __restrict__ h1h, const u16* __restrict__ h1l,
  const u16* __restrict__ h2h, const u16* __restrict__ h2l,
  const u16* __restrict__ h3h, const u16* __restrict__ h3l,
  const float* __restrict__ ab, float* __restrict__ rn)
{
  int lane=threadIdx.x&63;
  int gw=blockIdx.x*4+(threadIdx.x>>6), nw=gridDim.x*4;
  int cb=lane*4;
  float av[12], cv[12];
  #pragma unroll
  for(int s=0;s<3;s++){
    #pragma unroll
    for(int i=0;i<4;i++){ av[s*4+i]=ab[s*256+cb+i]; cv[s*4+i]=ab[768+s*256+cb+i]; }
  }
  for(int n=gw;n<NN;n+=nw){
    float ss=0.f;
    const u16* hh[3]={h1h,h2h,h3h};
    const u16* hl[3]={h1l,h2l,h3l};
    #pragma unroll
    for(int s=0;s<3;s++){
      ushort4 a4=*(const ushort4*)&hh[s][(long)n*256+cb];
      ushort4 c4=*(const ushort4*)&hl[s][(long)n*256+cb];
      float o0=(bf2f(a4.x)+bf2f(c4.x))*av[s*4+0]+cv[s*4+0];
      float o1=(bf2f(a4.y)+bf2f(c4.y))*av[s*4+1]+cv[s*4+1];
      float o2=(bf2f(a4.z)+bf2f(c4.z))*av[s*4+2]+cv[s*4+2];
      float o3=(bf2f(a4.w)+bf2f(c4.w))*av[s*4+3]+cv[s*4+3];
      ss+=o0*o0+o1*o1+o2*o2+o3*o3;
    }
    #pragma unroll
    for(int off=32;off;off>>=1) ss+=__shfl_xor(ss,off);
    if(lane==0) rn[n]=4.6f/fmaxf(sqrtf(ss),1e-12f);
  }
}

extern "C" void kernel_launch(void* const* d_in, const int* in_sizes, int n_in,
                              void* d_out, int out_size, void* d_ws, size_t ws_size,
                              hipStream_t stream)
{
  (void)in_sizes; (void)n_in; (void)out_size; (void)ws_size;
  const float* x   =(const float*)d_in[0];
  const int*   src =(const int*)d_in[1];
  const float* w1  =(const float*)d_in[3];
  const float* b1  =(const float*)d_in[4];
  const float* bn1g=(const float*)d_in[5];
  const float* bn1b=(const float*)d_in[6];
  const float* w2  =(const float*)d_in[7];
  const float* b2  =(const float*)d_in[8];
  const float* bn2g=(const float*)d_in[9];
  const float* bn2b=(const float*)d_in[10];
  const float* fc1 =(const float*)d_in[11];
  const float* a1l =(const float*)d_in[12];
  const float* a1r =(const float*)d_in[13];
  const float* bias1=(const float*)d_in[14];
  const float* fc2 =(const float*)d_in[15];
  const float* a2l =(const float*)d_in[16];
  const float* a2r =(const float*)d_in[17];
  const float* bias2=(const float*)d_in[18];
  const float* dbng=(const float*)d_in[19];
  const float* dbnb=(const float*)d_in[20];
  const float* cw  =(const float*)d_in[21];

  char* ws=(char*)d_ws;
  size_t off=0;
  auto take=[&](size_t bytes)->char*{ char* p=ws+off; off=(off+bytes+255)&~(size_t)255; return p; };
  float* stats =(float*)take(2048*4);
  float* params=(float*)take(4096*4);
  float* el    =(float*)take((size_t)MPAD*2*4);
  float* er    =(float*)take((size_t)MPAD*2*4);
  float* rnorm =(float*)take((size_t)MPAD*4);
  float* tvec  =(float*)take(256*4);
  float* alpha =(float*)take((size_t)NN*32*4);
  u16* fc1h=(u16*)take((size_t)65536*2);
  u16* fc1l=(u16*)take((size_t)65536*2);
  u16* fc2h=(u16*)take((size_t)65536*2);
  u16* fc2l=(u16*)take((size_t)65536*2);
  u16* wfh =(u16*)take((size_t)196608*2);
  u16* wfl =(u16*)take((size_t)196608*2);
  const size_t FB=(size_t)MPAD*256*2;
  u16* h0H  =(u16*)take(FB); u16* h0L  =(u16*)take(FB);  // conv h; later h3
  u16* h1H  =(u16*)take(FB); u16* h1L  =(u16*)take(FB);
  u16* h2H  =(u16*)take(FB); u16* h2L  =(u16*)take(FB);
  u16* featH=(u16*)d_out;   // feat (hi only) lives in d_out until the final GEMM

  float* xmom   =stats;        // 20
  float* stats2 =stats+32;     // 128
  float* dbn_raw=stats+512;    // 1536
  float* a1c1   =params;       // 64
  float* a2c2   =params+64;    // 128
  float* dbn_ab =params+256;   // 1536
  float* vprep  =params+2048;  // 2048 (8 x 256)

  hipMemsetAsync(stats,0,2048*4,stream);
  k_cvt2<<<dim3(256),dim3(256),0,stream>>>(fc1,fc1h,fc1l,65536);
  k_cvt2<<<dim3(256),dim3(256),0,stream>>>(fc2,fc2h,fc2l,65536);
  k_prep<<<dim3(1),dim3(256),0,stream>>>(fc1,fc2,a1l,a1r,a2l,a2r,vprep);
  k_xmom<<<dim3(128),dim3(256),0,stream>>>(x,xmom);
  k_fin1<<<dim3(1),dim3(64),0,stream>>>(xmom,w1,b1,bn1g,bn1b,a1c1);
  k_conv<0><<<dim3(1024),dim3(256),0,stream>>>(x,w1,b1,a1c1,w2,b2,a2c2,h0H,h0L,stats2,vprep,el,er);
  k_fin2<<<dim3(1),dim3(64),0,stream>>>(stats2,bn2g,bn2b,a2c2);
  k_conv<1><<<dim3(1024),dim3(256),0,stream>>>(x,w1,b1,a1c1,w2,b2,a2c2,h0H,h0L,stats2,vprep,el,er);

  dim3 gg(NT_M,2);
  // GAT layer 1
  k_gemm<0><<<gg,dim3(256),0,stream>>>(h0H,h0L,h0H,h0L,h0H,h0L,fc1h,fc1l,featH,
                                       (float*)nullptr,tvec,rnorm,256,8);
  k_alpha<<<dim3(391),dim3(256),0,stream>>>(el,er,src,alpha);
  k_aggr<1,1><<<dim3(2048),dim3(256),0,stream>>>(featH,alpha,src,bias1,h1H,h1L,dbn_raw,0,
                                                 vprep+1024,el,er);
  // GAT layer 2
  k_gemm<0><<<gg,dim3(256),0,stream>>>(h1H,h1L,h1H,h1L,h1H,h1L,fc2h,fc2l,featH,
                                       (float*)nullptr,tvec,rnorm,256,8);
  k_alpha<<<dim3(391),dim3(256),0,stream>>>(el,er,src,alpha);
  k_aggr<2,1><<<dim3(2048),dim3(256),0,stream>>>(featH,alpha,src,bias2,h2H,h2L,dbn_raw,256,
                                                 vprep+1024,el,er);
  // GAT layer 3
  k_gemm<0><<<gg,dim3(256),0,stream>>>(h2H,h2L,h2H,h2L,h2H,h2L,fc2h,fc2l,featH,
                                       (float*)nullptr,tvec,rnorm,256,8);
  k_alpha<<<dim3(391),dim3(256),0,stream>>>(el,er,src,alpha);
  k_aggr<3,0><<<dim3(2048),dim3(256),0,stream>>>(featH,alpha,src,bias2,h0H,h0L,dbn_raw,512,
                                                 vprep+1024,el,er);
  // dbn + folded cosine head
  k_dbnfin<<<dim3(3),dim3(256),0,stream>>>(dbn_raw,dbng,dbnb,dbn_ab);
  k_wfold<<<dim3(64),dim3(256),0,stream>>>(cw,dbn_ab,wfh,wfl,tvec);
  k_rnorm<<<dim3(1024),dim3(256),0,stream>>>(h1H,h1L,h2H,h2L,h0H,h0L,dbn_ab,rnorm);
  k_gemm<1><<<gg,dim3(256),0,stream>>>(h1H,h1L,h2H,h2L,h0H,h0L,wfh,wfl,(u16*)nullptr,
                                       (float*)d_out,tvec,rnorm,768,24);
}

// Round 5
// 1259.168 us; speedup vs baseline: 1.5091x; 1.2485x over previous
//
#include <hip/hip_runtime.h>

#define NN 100000
#define MPAD 100096
#define NT_M 782

typedef unsigned short u16;
typedef _Float16 f16x8 __attribute__((ext_vector_type(8)));
typedef __attribute__((ext_vector_type(4))) float f32x4;

__device__ __forceinline__ u16 f2h(float f){
  union { _Float16 h; u16 u; } v; v.h=(_Float16)f; return v.u;
}
__device__ __forceinline__ float h2f(u16 u){
  union { u16 u; _Float16 h; } v; v.u=u; return (float)v.h;
}
__device__ __forceinline__ void gload16(const void* g, void* l){
  __builtin_amdgcn_global_load_lds((const __attribute__((address_space(1))) void*)g,
                                   (__attribute__((address_space(3))) void*)l, 16, 0, 0);
}
__device__ __forceinline__ void lds_fence(){
  asm volatile("s_waitcnt lgkmcnt(0)" ::: "memory");
  __builtin_amdgcn_wave_barrier();
}

// ---------------- fp16 GEMM: C[m,n] = sum_k A[m,k]*B[n,k], BK=64, 128x128 tile
// A fp16 (up to 3 col-chunks of 256), B fp16 [256 x Bstride].
// EPI 0: store fp16 to cout. EPI 1: out = (acc + tvec[col])*rnorm[row] (f32).
template<int EPI>
__global__ __launch_bounds__(256) void k_gemm(
  const u16* __restrict__ a0, const u16* __restrict__ a1, const u16* __restrict__ a2,
  const u16* __restrict__ bmat, u16* __restrict__ cout,
  float* __restrict__ outf, const float* __restrict__ tvec,
  const float* __restrict__ rnorm, int Bstride, int KT)
{
  __shared__ u16 lds[2][2][8192];   // [buf][A,B][128 rows x 64 cols fp16]
  const int tid=threadIdx.x, lane=tid&63, wid=tid>>6;
  const int wr=wid>>1, wc=wid&1;
  const long m0=(long)blockIdx.x*128;
  const int n0=blockIdx.y*128;
  f32x4 acc[4][4]={};

  auto stageT=[&](u16* L, const u16* G, long rs){
    #pragma unroll
    for(int i=0;i<4;i++){
      int idx=i*256+tid;
      int row=idx>>3, slot=idx&7;
      int gc=(slot^(row&7))*8;            // inverse-swizzle on the GLOBAL side
      gload16(G+(long)row*rs+gc, L+idx*8);
    }
  };
  auto stage=[&](int buf,int kt){
    const u16* Ab=(kt<4)?a0:((kt<8)?a1:a2);
    int kc=(kt&3)*64;
    stageT(lds[buf][0], Ab+m0*256+kc, 256);
    stageT(lds[buf][1], bmat+(long)n0*Bstride+kt*64, Bstride);
  };
  stage(0,0);
  __syncthreads();
  int buf=0;
  for(int kt=0;kt<KT;kt++){
    if(kt+1<KT) stage(buf^1,kt+1);
    const u16* LA=lds[buf][0]; const u16* LB=lds[buf][1];
    #pragma unroll
    for(int kk=0;kk<2;kk++){
      f16x8 av[4], bv[4];
      #pragma unroll
      for(int mf=0;mf<4;mf++){
        int r=wr*64+mf*16+(lane&15);
        av[mf]=*(const f16x8*)&LA[r*64 + (((kk*4+(lane>>4))^(r&7))*8)];
      }
      #pragma unroll
      for(int nf=0;nf<4;nf++){
        int r=wc*64+nf*16+(lane&15);
        bv[nf]=*(const f16x8*)&LB[r*64 + (((kk*4+(lane>>4))^(r&7))*8)];
      }
      #pragma unroll
      for(int mf=0;mf<4;mf++){
        #pragma unroll
        for(int nf=0;nf<4;nf++)
          acc[mf][nf]=__builtin_amdgcn_mfma_f32_16x16x32_f16(av[mf],bv[nf],acc[mf][nf],0,0,0);
      }
    }
    __syncthreads();
    buf^=1;
  }
  #pragma unroll
  for(int mf=0;mf<4;mf++){
    #pragma unroll
    for(int j=0;j<4;j++){
      long row=m0+wr*64+mf*16+((lane>>4)*4)+j;
      if(row<NN){
        #pragma unroll
        for(int nf=0;nf<4;nf++){
          int col=n0+wc*64+nf*16+(lane&15);
          float v=acc[mf][nf][j];
          if(EPI==1) outf[row*256+col]=(v+tvec[col])*rnorm[row];
          else       cout[row*256+col]=f2h(v);
        }
      }
    }
  }
}

// ---------------- x patch moments
__global__ __launch_bounds__(256) void k_xmom(const float* __restrict__ x, float* __restrict__ stats){
  int t=blockIdx.x*blockDim.x+threadIdx.x, stride=gridDim.x*blockDim.x;
  int lane=threadIdx.x&63;
  float m[5]={0,0,0,0,0};
  float c[15]={0,0,0,0,0,0,0,0,0,0,0,0,0,0,0};
  for(int n=t;n<NN;n+=stride){
    float xr[60];
    #pragma unroll
    for(int i=0;i<15;i++){
      float4 v=*(const float4*)&x[(long)n*60+i*4];
      xr[i*4]=v.x; xr[i*4+1]=v.y; xr[i*4+2]=v.z; xr[i*4+3]=v.w;
    }
    #pragma unroll
    for(int p=0;p<12;p++){
      float vv[5]={xr[5*p],xr[5*p+1],xr[5*p+2],xr[5*p+3],xr[5*p+4]};
      #pragma unroll
      for(int k=0;k<5;k++) m[k]+=vv[k];
      int idx=0;
      #pragma unroll
      for(int k=0;k<5;k++){
        #pragma unroll
        for(int k2=k;k2<5;k2++){ c[idx]+=vv[k]*vv[k2]; idx++; }
      }
    }
  }
  float vals[20];
  #pragma unroll
  for(int i=0;i<5;i++) vals[i]=m[i];
  #pragma unroll
  for(int i=0;i<15;i++) vals[5+i]=c[i];
  #pragma unroll
  for(int i=0;i<20;i++){
    float v=vals[i];
    #pragma unroll
    for(int off=32;off;off>>=1) v+=__shfl_xor(v,off);
    if(lane==0) atomicAdd(&stats[i],v);
  }
}

__global__ void k_fin1(const float* __restrict__ stats, const float* __restrict__ w1,
                       const float* __restrict__ b1, const float* __restrict__ g,
                       const float* __restrict__ bt, float* __restrict__ a1c1){
  int c=threadIdx.x;
  if(c>=32) return;
  const float inv=1.0f/(NN*12.0f);
  float mu[5];
  for(int k=0;k<5;k++) mu[k]=stats[k]*inv;
  float C[5][5];
  int idx=5;
  for(int k=0;k<5;k++) for(int k2=k;k2<5;k2++){ float v=stats[idx++]*inv; C[k][k2]=v; C[k2][k]=v; }
  float wv[5];
  for(int k=0;k<5;k++) wv[k]=w1[c*5+k];
  float bb=b1[c];
  float mean=bb, e2=bb*bb;
  for(int k=0;k<5;k++){ mean+=wv[k]*mu[k]; e2+=2.f*bb*wv[k]*mu[k]; }
  for(int k=0;k<5;k++) for(int k2=0;k2<5;k2++) e2+=wv[k]*wv[k2]*C[k][k2];
  float var=e2-mean*mean;
  float a=g[c]*rsqrtf(var+1e-5f);
  a1c1[c]=a; a1c1[32+c]=bt[c]-mean*a;
}

// transform vectors: vL[h][k] = sum_c fc[h*128+c, k] * a[h,c]
__global__ void k_prep(const float* __restrict__ fc1, const float* __restrict__ fc2,
                       const float* __restrict__ a1l, const float* __restrict__ a1r,
                       const float* __restrict__ a2l, const float* __restrict__ a2r,
                       float* __restrict__ vprep){
  int k=threadIdx.x;
  float acc[8]={0,0,0,0,0,0,0,0};
  for(int r=0;r<256;r++){
    int h=r>>7, c=r&127;
    float f1=fc1[r*256+k], f2=fc2[r*256+k];
    acc[0+h]+=f1*a1l[h*128+c];
    acc[2+h]+=f1*a1r[h*128+c];
    acc[4+h]+=f2*a2l[h*128+c];
    acc[6+h]+=f2*a2r[h*128+c];
  }
  #pragma unroll
  for(int v=0;v<8;v++) vprep[v*256+k]=acc[v];
}

// conv1->bn1/relu->conv2: write raw y2 (f32) + BN2 stats (single compute pass)
__global__ __launch_bounds__(256) void k_conv(const float* __restrict__ x,
  const float* __restrict__ w1, const float* __restrict__ b1,
  const float* __restrict__ a1c1, const float* __restrict__ w2,
  const float* __restrict__ b2, float* __restrict__ y2, float* __restrict__ stats2)
{
  __shared__ float w2s[64*97];
  __shared__ float w1s[160], a1s[32], c1s[32], b1s[32], b2s[64];
  __shared__ float xs[4][64];
  __shared__ float z1s[4][384];
  __shared__ float bsum[128];
  int tid=threadIdx.x, lane=tid&63, w=tid>>6;
  for(int i=tid;i<6144;i+=256) w2s[(i/96)*97+(i%96)]=w2[i];
  if(tid<160) w1s[tid]=w1[tid];
  if(tid<32){ a1s[tid]=a1c1[tid]; c1s[tid]=a1c1[32+tid]; b1s[tid]=b1[tid]; }
  if(tid<64) b2s[tid]=b2[tid];
  if(tid<128) bsum[tid]=0.f;
  __syncthreads();
  float ssum=0.f, ssq=0.f;
  int gw=blockIdx.x*4+w, nw=gridDim.x*4;
  for(int n=gw;n<NN;n+=nw){
    if(lane<60) xs[w][lane]=x[(long)n*60+lane];
    lds_fence();
    {
      int c=lane>>1, pb=(lane&1)*6;
      float av=a1s[c], cv=c1s[c], bb=b1s[c];
      #pragma unroll
      for(int i=0;i<6;i++){
        int p=pb+i;
        float y=bb;
        #pragma unroll
        for(int k=0;k<5;k++) y+=xs[w][5*p+k]*w1s[c*5+k];
        z1s[w][c*12+p]=fmaxf(y*av+cv,0.f);
      }
    }
    lds_fence();
    {
      int c2=lane;
      float acc0=b2s[c2],acc1=b2s[c2],acc2=b2s[c2],acc3=b2s[c2];
      #pragma unroll
      for(int ci=0;ci<32;ci++){
        float4 za=*(const float4*)&z1s[w][ci*12];
        float4 zb=*(const float4*)&z1s[w][ci*12+4];
        float4 zc=*(const float4*)&z1s[w][ci*12+8];
        float w0=w2s[c2*97+ci*3], wv1=w2s[c2*97+ci*3+1], wv2=w2s[c2*97+ci*3+2];
        acc0 += za.x*w0+za.y*wv1+za.z*wv2;
        acc1 += za.w*w0+zb.x*wv1+zb.y*wv2;
        acc2 += zb.z*w0+zb.w*wv1+zc.x*wv2;
        acc3 += zc.y*w0+zc.z*wv1+zc.w*wv2;
      }
      float4 o; o.x=acc0; o.y=acc1; o.z=acc2; o.w=acc3;
      *(float4*)&y2[(long)n*256+c2*4]=o;
      ssum+=acc0+acc1+acc2+acc3;
      ssq+=acc0*acc0+acc1*acc1+acc2*acc2+acc3*acc3;
    }
    lds_fence();
  }
  atomicAdd(&bsum[lane],ssum);
  atomicAdd(&bsum[64+lane],ssq);
  __syncthreads();
  if(tid<128) atomicAdd(&stats2[tid],bsum[tid]);
}

__global__ void k_fin2(const float* __restrict__ stats2, const float* __restrict__ g,
                       const float* __restrict__ bt, float* __restrict__ a2c2){
  int c=threadIdx.x;
  if(c>=64) return;
  const float inv=1.0f/(NN*4.0f);
  float mean=stats2[c]*inv;
  float var=stats2[64+c]*inv-mean*mean;
  float a=g[c]*rsqrtf(var+1e-5f);
  a2c2[c]=a; a2c2[64+c]=bt[c]-mean*a;
}

// apply bn2+relu to y2 -> h fp16; + layer-1 el/er epilogue (fp32)
__global__ __launch_bounds__(256) void k_happ(const float* __restrict__ y2,
  const float* __restrict__ a2c2, const float* __restrict__ vprep,
  u16* __restrict__ h, float* __restrict__ elv, float* __restrict__ erv)
{
  int lane=threadIdx.x&63;
  int gw=blockIdx.x*4+(threadIdx.x>>6), nw=gridDim.x*4;
  float a2=a2c2[lane], c2v=a2c2[64+lane];   // channel == lane
  int cb=lane*4;
  float4 vl0=*(const float4*)&vprep[cb];
  float4 vl1=*(const float4*)&vprep[256+cb];
  float4 vr0=*(const float4*)&vprep[512+cb];
  float4 vr1=*(const float4*)&vprep[768+cb];
  for(int n=gw;n<NN;n+=nw){
    float4 y=*(const float4*)&y2[(long)n*256+cb];
    float o0=fmaxf(y.x*a2+c2v,0.f), o1=fmaxf(y.y*a2+c2v,0.f);
    float o2=fmaxf(y.z*a2+c2v,0.f), o3=fmaxf(y.w*a2+c2v,0.f);
    ushort4 o; o.x=f2h(o0); o.y=f2h(o1); o.z=f2h(o2); o.w=f2h(o3);
    *(ushort4*)&h[(long)n*256+cb]=o;
    float pl0=o0*vl0.x+o1*vl0.y+o2*vl0.z+o3*vl0.w;
    float pl1=o0*vl1.x+o1*vl1.y+o2*vl1.z+o3*vl1.w;
    float pr0=o0*vr0.x+o1*vr0.y+o2*vr0.z+o3*vr0.w;
    float pr1=o0*vr1.x+o1*vr1.y+o2*vr1.z+o3*vr1.w;
    #pragma unroll
    for(int off=32;off;off>>=1){
      pl0+=__shfl_xor(pl0,off); pl1+=__shfl_xor(pl1,off);
      pr0+=__shfl_xor(pr0,off); pr1+=__shfl_xor(pr1,off);
    }
    if(lane==0){ elv[2*n]=pl0; elv[2*n+1]=pl1; erv[2*n]=pr0; erv[2*n+1]=pr1; }
  }
}

// f32 -> fp16
__global__ void k_cvth(const float* __restrict__ in, u16* __restrict__ out, int n){
  int i=blockIdx.x*blockDim.x+threadIdx.x;
  if(i<n) out[i]=f2h(in[i]);
}

// fold dbn scale into l2-normalized cos_W rows (fp16); t[r] = sum_k c_k * Wn_k / ||Wn||
__global__ __launch_bounds__(256) void k_wfold(const float* __restrict__ cw, const float* __restrict__ ab,
  u16* __restrict__ wh, float* __restrict__ tvec)
{
  int lane=threadIdx.x&63;
  int r=blockIdx.x*4+(threadIdx.x>>6);
  if(r>=256) return;
  float v[12]; float ss=0.f, tn=0.f;
  #pragma unroll
  for(int i=0;i<12;i++){
    int col=i*64+lane;
    v[i]=cw[r*768+col];
    ss+=v[i]*v[i];
    tn+=v[i]*ab[768+col];
  }
  #pragma unroll
  for(int off=32;off;off>>=1){ ss+=__shfl_xor(ss,off); tn+=__shfl_xor(tn,off); }
  float sc=1.0f/fmaxf(sqrtf(ss),1e-12f);
  #pragma unroll
  for(int i=0;i<12;i++){
    int col=i*64+lane;
    wh[r*768+col]=f2h(v[i]*sc*ab[col]);
  }
  if(lane==0) tvec[r]=tn*sc;
}

// per-node softmax over 16 contiguous edges -> alpha[n*32 + 2j + head]
__global__ __launch_bounds__(256) void k_alpha(const float* __restrict__ el, const float* __restrict__ er,
  const int* __restrict__ srcv, float* __restrict__ alpha)
{
  int n=blockIdx.x*blockDim.x+threadIdx.x;
  if(n>=NN) return;
  int sidx[16];
  #pragma unroll
  for(int j=0;j<16;j+=4){
    int4 v=*(const int4*)&srcv[n*16+j];
    sidx[j]=v.x; sidx[j+1]=v.y; sidx[j+2]=v.z; sidx[j+3]=v.w;
  }
  float er0=er[2*n], er1=er[2*n+1];
  float e0[16], e1[16];
  float mx0=-1e30f, mx1=-1e30f;
  #pragma unroll
  for(int j=0;j<16;j++){
    float a=el[2*sidx[j]]+er0;
    float bb=el[2*sidx[j]+1]+er1;
    a = a>0.f? a : 0.2f*a;
    bb = bb>0.f? bb : 0.2f*bb;
    e0[j]=a; e1[j]=bb;
    mx0=fmaxf(mx0,a); mx1=fmaxf(mx1,bb);
  }
  float d0=0.f,d1=0.f;
  #pragma unroll
  for(int j=0;j<16;j++){
    e0[j]=__expf(e0[j]-mx0); d0+=e0[j];
    e1[j]=__expf(e1[j]-mx1); d1+=e1[j];
  }
  float r0=1.f/fmaxf(d0,1e-12f), r1=1.f/fmaxf(d1,1e-12f);
  #pragma unroll
  for(int j=0;j<16;j++){
    float2 o; o.x=e0[j]*r0; o.y=e1[j]*r1;
    ((float2*)alpha)[(long)n*16+j]=o;
  }
}

template<int ACT> __device__ __forceinline__ float actf(float g);
template<> __device__ __forceinline__ float actf<1>(float g){
  float t=tanhf(g);
  float ls=fminf(g,0.f)-log1pf(__expf(-fabsf(g)));
  return fmaxf(g,0.f)+t+ls;
}
template<> __device__ __forceinline__ float actf<2>(float g){ return tanhf(g); }
template<> __device__ __forceinline__ float actf<3>(float g){ return fmaxf(g,0.f); }

// gather-aggregate with precomputed alpha (fp16 feat); fp16 h store + dbn stats; optional next el/er
template<int ACT,int WELR>
__global__ __launch_bounds__(256) void k_aggr(const u16* __restrict__ fH,
  const float* __restrict__ alpha, const int* __restrict__ srcv, const float* __restrict__ bias,
  u16* __restrict__ hH, float* __restrict__ dbn_raw, int col_base,
  const float* __restrict__ vnext, float* __restrict__ elo, float* __restrict__ ero)
{
  __shared__ float bsum[256], bsq[256];
  int tid=threadIdx.x, lane=tid&63;
  bsum[tid]=0.f; bsq[tid]=0.f;
  __syncthreads();
  int gw=blockIdx.x*4+(tid>>6), nw=gridDim.x*4;
  int head=lane>>5, cb=lane*4;
  float4 b4=*(const float4*)&bias[cb];
  float4 vl0={0,0,0,0},vl1={0,0,0,0},vr0={0,0,0,0},vr1={0,0,0,0};
  if(WELR){
    vl0=*(const float4*)&vnext[cb];
    vl1=*(const float4*)&vnext[256+cb];
    vr0=*(const float4*)&vnext[512+cb];
    vr1=*(const float4*)&vnext[768+cb];
  }
  float s[4]={0,0,0,0}, q[4]={0,0,0,0};
  for(int n=gw;n<NN;n+=nw){
    int sidx[16];
    #pragma unroll
    for(int j=0;j<16;j+=4){
      int4 v=*(const int4*)&srcv[n*16+j];
      sidx[j]=v.x; sidx[j+1]=v.y; sidx[j+2]=v.z; sidx[j+3]=v.w;
    }
    float a0=b4.x,a1=b4.y,a2=b4.z,a3=b4.w;
    #pragma unroll
    for(int j=0;j<16;j++){
      float2 aw2=((const float2*)alpha)[(long)n*16+j];
      float aw = head? aw2.y : aw2.x;
      ushort4 f=*(const ushort4*)&fH[(long)sidx[j]*256+cb];
      a0+=aw*h2f(f.x); a1+=aw*h2f(f.y);
      a2+=aw*h2f(f.z); a3+=aw*h2f(f.w);
    }
    float h0=actf<ACT>(a0), h1=actf<ACT>(a1), h2=actf<ACT>(a2), h3=actf<ACT>(a3);
    ushort4 o; o.x=f2h(h0); o.y=f2h(h1); o.z=f2h(h2); o.w=f2h(h3);
    *(ushort4*)&hH[(long)n*256+cb]=o;
    s[0]+=h0; s[1]+=h1; s[2]+=h2; s[3]+=h3;
    q[0]+=h0*h0; q[1]+=h1*h1; q[2]+=h2*h2; q[3]+=h3*h3;
    if(WELR){
      float pl0=h0*vl0.x+h1*vl0.y+h2*vl0.z+h3*vl0.w;
      float pl1=h0*vl1.x+h1*vl1.y+h2*vl1.z+h3*vl1.w;
      float pr0=h0*vr0.x+h1*vr0.y+h2*vr0.z+h3*vr0.w;
      float pr1=h0*vr1.x+h1*vr1.y+h2*vr1.z+h3*vr1.w;
      #pragma unroll
      for(int off2=32;off2;off2>>=1){
        pl0+=__shfl_xor(pl0,off2); pl1+=__shfl_xor(pl1,off2);
        pr0+=__shfl_xor(pr0,off2); pr1+=__shfl_xor(pr1,off2);
      }
      if(lane==0){ elo[2*n]=pl0; elo[2*n+1]=pl1; ero[2*n]=pr0; ero[2*n+1]=pr1; }
    }
  }
  #pragma unroll
  for(int i=0;i<4;i++){ atomicAdd(&bsum[cb+i], s[i]); atomicAdd(&bsq[cb+i], q[i]); }
  __syncthreads();
  atomicAdd(&dbn_raw[col_base+tid], bsum[tid]);
  atomicAdd(&dbn_raw[768+col_base+tid], bsq[tid]);
}

__global__ void k_dbnfin(const float* __restrict__ raw, const float* __restrict__ g,
                         const float* __restrict__ b, float* __restrict__ ab){
  int c=blockIdx.x*blockDim.x+threadIdx.x;
  if(c<768){
    float mean=raw[c]*(1.0f/NN);
    float var=raw[768+c]*(1.0f/NN)-mean*mean;
    float a=g[c]*rsqrtf(var+1e-5f);
    ab[c]=a; ab[768+c]=b[c]-mean*a;
  }
}

// rnorm[n] = 4.6 / || dbn(h1|h2|h3) ||  from fp16 h
__global__ __launch_bounds__(256) void k_rnorm(
  const u16* __restrict__ h1h, const u16* __restrict__ h2h, const u16* __restrict__ h3h,
  const float* __restrict__ ab, float* __restrict__ rn)
{
  int lane=threadIdx.x&63;
  int gw=blockIdx.x*4+(threadIdx.x>>6), nw=gridDim.x*4;
  int cb=lane*4;
  float av[12], cv[12];
  #pragma unroll
  for(int s=0;s<3;s++){
    #pragma unroll
    for(int i=0;i<4;i++){ av[s*4+i]=ab[s*256+cb+i]; cv[s*4+i]=ab[768+s*256+cb+i]; }
  }
  for(int n=gw;n<NN;n+=nw){
    float ss=0.f;
    const u16* hh[3]={h1h,h2h,h3h};
    #pragma unroll
    for(int s=0;s<3;s++){
      ushort4 a4=*(const ushort4*)&hh[s][(long)n*256+cb];
      float o0=h2f(a4.x)*av[s*4+0]+cv[s*4+0];
      float o1=h2f(a4.y)*av[s*4+1]+cv[s*4+1];
      float o2=h2f(a4.z)*av[s*4+2]+cv[s*4+2];
      float o3=h2f(a4.w)*av[s*4+3]+cv[s*4+3];
      ss+=o0*o0+o1*o1+o2*o2+o3*o3;
    }
    #pragma unroll
    for(int off=32;off;off>>=1) ss+=__shfl_xor(ss,off);
    if(lane==0) rn[n]=4.6f/fmaxf(sqrtf(ss),1e-12f);
  }
}

extern "C" void kernel_launch(void* const* d_in, const int* in_sizes, int n_in,
                              void* d_out, int out_size, void* d_ws, size_t ws_size,
                              hipStream_t stream)
{
  (void)in_sizes; (void)n_in; (void)out_size; (void)ws_size;
  const float* x   =(const float*)d_in[0];
  const int*   src =(const int*)d_in[1];
  const float* w1  =(const float*)d_in[3];
  const float* b1  =(const float*)d_in[4];
  const float* bn1g=(const float*)d_in[5];
  const float* bn1b=(const float*)d_in[6];
  const float* w2  =(const float*)d_in[7];
  const float* b2  =(const float*)d_in[8];
  const float* bn2g=(const float*)d_in[9];
  const float* bn2b=(const float*)d_in[10];
  const float* fc1 =(const float*)d_in[11];
  const float* a1l =(const float*)d_in[12];
  const float* a1r =(const float*)d_in[13];
  const float* bias1=(const float*)d_in[14];
  const float* fc2 =(const float*)d_in[15];
  const float* a2l =(const float*)d_in[16];
  const float* a2r =(const float*)d_in[17];
  const float* bias2=(const float*)d_in[18];
  const float* dbng=(const float*)d_in[19];
  const float* dbnb=(const float*)d_in[20];
  const float* cw  =(const float*)d_in[21];

  char* ws=(char*)d_ws;
  size_t off=0;
  auto take=[&](size_t bytes)->char*{ char* p=ws+off; off=(off+bytes+255)&~(size_t)255; return p; };
  float* stats =(float*)take(2048*4);
  float* params=(float*)take(4096*4);
  float* el    =(float*)take((size_t)MPAD*2*4);
  float* er    =(float*)take((size_t)MPAD*2*4);
  float* rnorm =(float*)take((size_t)MPAD*4);
  float* tvec  =(float*)take(256*4);
  float* alpha =(float*)take((size_t)NN*32*4);
  u16* fc1h=(u16*)take((size_t)65536*2);
  u16* fc2h=(u16*)take((size_t)65536*2);
  u16* wfh =(u16*)take((size_t)196608*2);
  float* y2 =(float*)take((size_t)MPAD*256*4);
  const size_t FB=(size_t)MPAD*256*2;
  u16* h0H  =(u16*)take(FB);   // conv h; later h3
  u16* h1H  =(u16*)take(FB);
  u16* h2H  =(u16*)take(FB);
  u16* featH=(u16*)d_out;      // fp16 feat lives in d_out until the final GEMM

  float* xmom   =stats;        // 20
  float* stats2 =stats+32;     // 128
  float* dbn_raw=stats+512;    // 1536
  float* a1c1   =params;       // 64
  float* a2c2   =params+64;    // 128
  float* dbn_ab =params+256;   // 1536
  float* vprep  =params+2048;  // 2048 (8 x 256)

  hipMemsetAsync(stats,0,2048*4,stream);
  k_cvth<<<dim3(256),dim3(256),0,stream>>>(fc1,fc1h,65536);
  k_cvth<<<dim3(256),dim3(256),0,stream>>>(fc2,fc2h,65536);
  k_prep<<<dim3(1),dim3(256),0,stream>>>(fc1,fc2,a1l,a1r,a2l,a2r,vprep);
  k_xmom<<<dim3(128),dim3(256),0,stream>>>(x,xmom);
  k_fin1<<<dim3(1),dim3(64),0,stream>>>(xmom,w1,b1,bn1g,bn1b,a1c1);
  k_conv<<<dim3(1024),dim3(256),0,stream>>>(x,w1,b1,a1c1,w2,b2,y2,stats2);
  k_fin2<<<dim3(1),dim3(64),0,stream>>>(stats2,bn2g,bn2b,a2c2);
  k_happ<<<dim3(2048),dim3(256),0,stream>>>(y2,a2c2,vprep,h0H,el,er);

  dim3 gg(NT_M,2);
  // GAT layer 1
  k_gemm<0><<<gg,dim3(256),0,stream>>>(h0H,h0H,h0H,fc1h,featH,(float*)nullptr,tvec,rnorm,256,4);
  k_alpha<<<dim3(391),dim3(256),0,stream>>>(el,er,src,alpha);
  k_aggr<1,1><<<dim3(2048),dim3(256),0,stream>>>(featH,alpha,src,bias1,h1H,dbn_raw,0,
                                                 vprep+1024,el,er);
  // GAT layer 2
  k_gemm<0><<<gg,dim3(256),0,stream>>>(h1H,h1H,h1H,fc2h,featH,(float*)nullptr,tvec,rnorm,256,4);
  k_alpha<<<dim3(391),dim3(256),0,stream>>>(el,er,src,alpha);
  k_aggr<2,1><<<dim3(2048),dim3(256),0,stream>>>(featH,alpha,src,bias2,h2H,dbn_raw,256,
                                                 vprep+1024,el,er);
  // GAT layer 3
  k_gemm<0><<<gg,dim3(256),0,stream>>>(h2H,h2H,h2H,fc2h,featH,(float*)nullptr,tvec,rnorm,256,4);
  k_alpha<<<dim3(391),dim3(256),0,stream>>>(el,er,src,alpha);
  k_aggr<3,0><<<dim3(2048),dim3(256),0,stream>>>(featH,alpha,src,bias2,h0H,dbn_raw,512,
                                                 vprep+1024,el,er);
  // dbn + folded cosine head
  k_dbnfin<<<dim3(3),dim3(256),0,stream>>>(dbn_raw,dbng,dbnb,dbn_ab);
  k_wfold<<<dim3(64),dim3(256),0,stream>>>(cw,dbn_ab,wfh,tvec);
  k_rnorm<<<dim3(1024),dim3(256),0,stream>>>(h1H,h2H,h0H,dbn_ab,rnorm);
  k_gemm<1><<<gg,dim3(256),0,stream>>>(h1H,h2H,h0H,wfh,(u16*)nullptr,
                                       (float*)d_out,tvec,rnorm,768,12);
}